// Round 6
// baseline (189.279 us; speedup 1.0000x reference)
//
#include <hip/hip_runtime.h>
#include <cstdint>
#include <cstddef>

// ---------- types ----------
typedef __bf16 bf8_t __attribute__((ext_vector_type(8)));
typedef float  f4_t  __attribute__((ext_vector_type(4)));

static __device__ __forceinline__ f4_t mfma16(bf8_t a, bf8_t b, f4_t c) {
    return __builtin_amdgcn_mfma_f32_16x16x32_bf16(a, b, c, 0, 0, 0);
}

#if defined(__has_builtin) && __has_builtin(__builtin_amdgcn_exp2f)
#define EXP2F(x) __builtin_amdgcn_exp2f(x)
#else
#define EXP2F(x) exp2f(x)
#endif

// global -> LDS direct DMA, 16B per lane (wave-uniform base, lane i at base+i*16)
static __device__ __forceinline__ void async_ld16(const __bf16* g, __bf16* l) {
    __builtin_amdgcn_global_load_lds(
        (const __attribute__((address_space(1))) void*)(uintptr_t)g,
        (__attribute__((address_space(3))) void*)(uintptr_t)l, 16, 0, 0);
}

// B=2, T=2048, E=1024, H=16, D=64.  M = B*T = 4096.

// ---------- prep: fp32 -> bf16 for X (4096x1024) and Wo (1024x1024) ----------
__global__ void __launch_bounds__(256) prep_convert(const float* __restrict__ X,
                                                    const float* __restrict__ Wo,
                                                    __bf16* __restrict__ Xbf,
                                                    __bf16* __restrict__ Wobf) {
    size_t bx = blockIdx.x;
    const float* src; __bf16* dst; size_t base;
    if (bx < 2048) { src = X;  dst = Xbf;  base = bx * 2048; }
    else           { src = Wo; dst = Wobf; base = (bx - 2048) * 2048; }
    size_t i = base + (size_t)threadIdx.x * 8;
    float4 a = *(const float4*)(src + i);
    float4 b = *(const float4*)(src + i + 4);
    bf8_t o;
    o[0] = (__bf16)a.x; o[1] = (__bf16)a.y; o[2] = (__bf16)a.z; o[3] = (__bf16)a.w;
    o[4] = (__bf16)b.x; o[5] = (__bf16)b.y; o[6] = (__bf16)b.z; o[7] = (__bf16)b.w;
    *(bf8_t*)(dst + i) = o;
}

// ---------- prep: W [H,E,D] fp32 -> Wt [H*D, E] bf16 (B^T layout) ----------
__global__ void __launch_bounds__(256) wtrans(const float* __restrict__ Wq,
                                              const float* __restrict__ Wk,
                                              const float* __restrict__ Wv,
                                              __bf16* __restrict__ Wqt,
                                              __bf16* __restrict__ Wkt,
                                              __bf16* __restrict__ Wvt) {
    const float* W; __bf16* Wt;
    if (blockIdx.y == 0)      { W = Wq; Wt = Wqt; }
    else if (blockIdx.y == 1) { W = Wk; Wt = Wkt; }
    else                      { W = Wv; Wt = Wvt; }
    int h = blockIdx.x >> 4, eb = blockIdx.x & 15;
    __shared__ float tile[64][65];
    int tx = threadIdx.x;
    int e = tx >> 2, dg = (tx & 3) * 16;
    const float* src = W + ((size_t)h * 1024 + eb * 64 + e) * 64 + dg;
#pragma unroll
    for (int i = 0; i < 4; ++i) {
        float4 v = *(const float4*)(src + i * 4);
        tile[dg + i * 4 + 0][e] = v.x;
        tile[dg + i * 4 + 1][e] = v.y;
        tile[dg + i * 4 + 2][e] = v.z;
        tile[dg + i * 4 + 3][e] = v.w;
    }
    __syncthreads();
    int d = tx >> 2, eg = (tx & 3) * 16;
    __bf16* dst = Wt + (size_t)(h * 64 + d) * 1024 + eb * 64 + eg;
    bf8_t o0, o1;
#pragma unroll
    for (int i = 0; i < 8; ++i) o0[i] = (__bf16)tile[d][eg + i];
#pragma unroll
    for (int i = 0; i < 8; ++i) o1[i] = (__bf16)tile[d][eg + 8 + i];
    *(bf8_t*)dst       = o0;
    *(bf8_t*)(dst + 8) = o1;
}

// ---------- m97-style mainloop: C[128x128] tile of A[M,1024] x Bt[N,1024]^T ----
// 4 waves in 2x2, each wave 64x64 via 4x4 16x16 frags. BK=64.
static __device__ __forceinline__ void gemm_tile128(const __bf16* __restrict__ A,
                                                    const __bf16* __restrict__ Bt,
                                                    __bf16* As, __bf16* Bs,
                                                    int m0, int n0, f4_t acc[4][4]) {
    const int tid  = threadIdx.x;
    const int lane = tid & 63;
    const int wv   = tid >> 6;
    const int lrow = lane >> 3;
    const int lsc  = lane & 7;
    const int quad = lane >> 4;
    const int l15  = lane & 15;
    const int wm = (wv & 1) * 64;
    const int wn = (wv >> 1) * 64;
    f4_t zero = {0.f, 0.f, 0.f, 0.f};
#pragma unroll
    for (int mi = 0; mi < 4; ++mi)
#pragma unroll
        for (int ni = 0; ni < 4; ++ni) acc[mi][ni] = zero;

    for (int kb = 0; kb < 16; ++kb) {
#pragma unroll
        for (int j = 0; j < 4; ++j) {
            int row = wv * 32 + j * 8 + lrow;
            int lc  = lsc ^ (row & 7);
            async_ld16(A + (size_t)(m0 + row) * 1024 + kb * 64 + lc * 8,
                       As + (wv * 32 + j * 8) * 64);
            async_ld16(Bt + (size_t)(n0 + row) * 1024 + kb * 64 + lc * 8,
                       Bs + (wv * 32 + j * 8) * 64);
        }
        __syncthreads();
#pragma unroll
        for (int ks = 0; ks < 2; ++ks) {
            bf8_t af[4], bfr[4];
#pragma unroll
            for (int mi = 0; mi < 4; ++mi) {
                int row = wm + mi * 16 + l15;
                int ch  = (ks * 4 + quad) ^ (row & 7);
                af[mi] = *(const bf8_t*)(As + row * 64 + ch * 8);
            }
#pragma unroll
            for (int ni = 0; ni < 4; ++ni) {
                int row = wn + ni * 16 + l15;
                int ch  = (ks * 4 + quad) ^ (row & 7);
                bfr[ni] = *(const bf8_t*)(Bs + row * 64 + ch * 8);
            }
#pragma unroll
            for (int mi = 0; mi < 4; ++mi)
#pragma unroll
                for (int ni = 0; ni < 4; ++ni)
                    acc[mi][ni] = mfma16(af[mi], bfr[ni], acc[mi][ni]);
        }
        __syncthreads();
    }
}

// ---------- projections: X @ W{q,k,v}. Q,K -> [B,H,T,D]; V -> V^T [B,H,D,T].
// K is pre-scaled by 0.125*log2(e) so attention can use exp2 directly.
__global__ void __launch_bounds__(256) gemm_proj(const __bf16* __restrict__ Xbf,
                                                 const __bf16* __restrict__ Wqt,
                                                 const __bf16* __restrict__ Wkt,
                                                 const __bf16* __restrict__ Wvt,
                                                 __bf16* __restrict__ Qb,
                                                 __bf16* __restrict__ Kb,
                                                 __bf16* __restrict__ Vt) {
    __shared__ __bf16 smem[17408];     // union: As(8192)+Bs(8192) | 128x136 transpose
    __bf16* As = smem;
    __bf16* Bs = smem + 8192;
    int which = blockIdx.y;
    const __bf16* Bt = which == 0 ? Wqt : (which == 1 ? Wkt : Wvt);
    int m0 = ((int)blockIdx.x >> 3) * 128;
    int n0 = ((int)blockIdx.x & 7) * 128;
    f4_t acc[4][4];
    gemm_tile128(Xbf, Bt, As, Bs, m0, n0, acc);
    const int lane = threadIdx.x & 63, wv = threadIdx.x >> 6;
    const int quad = lane >> 4, l15 = lane & 15;
    const int wm = (wv & 1) * 64, wn = (wv >> 1) * 64;
    if (which < 2) {
        __bf16* C = which ? Kb : Qb;
        const float scl = which ? 0.18033688f : 1.0f;   // 0.125 * log2(e) folded into K
#pragma unroll
        for (int mi = 0; mi < 4; ++mi)
#pragma unroll
            for (int ni = 0; ni < 4; ++ni)
#pragma unroll
                for (int r = 0; r < 4; ++r) {
                    int m = m0 + wm + mi * 16 + quad * 4 + r;
                    int n = n0 + wn + ni * 16 + l15;
                    int b = m >> 11, t = m & 2047;
                    int h = n >> 6,  d = n & 63;
                    C[((size_t)(b * 16 + h) * 2048 + t) * 64 + d] = (__bf16)(acc[mi][ni][r] * scl);
                }
    } else {
        // V^T epilogue: acc -> LDS [n_loc][m_loc] (stride 136) -> coalesced rows
        const int STR = 136;
#pragma unroll
        for (int mi = 0; mi < 4; ++mi)
#pragma unroll
            for (int ni = 0; ni < 4; ++ni)
#pragma unroll
                for (int r = 0; r < 4; ++r) {
                    int ml = wm + mi * 16 + quad * 4 + r;   // 0..127 (t)
                    int nl = wn + ni * 16 + l15;            // 0..127 (h,d)
                    smem[nl * STR + ml] = (__bf16)acc[mi][ni][r];
                }
        __syncthreads();
        int b = m0 >> 11, tg0 = m0 & 2047;
        int nl = (int)threadIdx.x >> 1;
        int tc = ((int)threadIdx.x & 1) * 64;
        int n = n0 + nl, h = n >> 6, d = n & 63;
        __bf16* dst = Vt + ((size_t)(b * 16 + h) * 64 + d) * 2048 + tg0 + tc;
        const __bf16* srcl = smem + nl * STR + tc;
#pragma unroll
        for (int k = 0; k < 8; ++k)
            *(bf8_t*)(dst + k * 8) = *(const bf8_t*)(srcl + k * 8);
    }
}

// ---------- GEMM mainloop (128x64 tile) kept for gemm_out (grid 512 = 2/CU) --
static __device__ __forceinline__ void gemm_tile(const __bf16* __restrict__ A,
                                                 const __bf16* __restrict__ Bt,
                                                 __bf16* As, __bf16* Bs,
                                                 int m0, int n0, f4_t acc[4][2]) {
    const int tid  = threadIdx.x;
    const int lane = tid & 63;
    const int wv   = tid >> 6;
    const int lrow = lane >> 3;
    const int lsc  = lane & 7;
    const int quad = lane >> 4;
    const int l15  = lane & 15;
    const int wm = (wv & 1) * 64;
    const int wn = (wv >> 1) * 32;
    f4_t zero = {0.f, 0.f, 0.f, 0.f};
#pragma unroll
    for (int mi = 0; mi < 4; ++mi)
#pragma unroll
        for (int ni = 0; ni < 2; ++ni) acc[mi][ni] = zero;

    for (int kb = 0; kb < 16; ++kb) {
#pragma unroll
        for (int j = 0; j < 4; ++j) {
            int row = wv * 32 + j * 8 + lrow;
            int lc  = lsc ^ (row & 7);
            async_ld16(A + (size_t)(m0 + row) * 1024 + kb * 64 + lc * 8,
                       As + (wv * 32 + j * 8) * 64);
        }
#pragma unroll
        for (int j = 0; j < 2; ++j) {
            int row = wv * 16 + j * 8 + lrow;
            int lc  = lsc ^ (row & 7);
            async_ld16(Bt + (size_t)(n0 + row) * 1024 + kb * 64 + lc * 8,
                       Bs + (wv * 16 + j * 8) * 64);
        }
        __syncthreads();
#pragma unroll
        for (int ks = 0; ks < 2; ++ks) {
            bf8_t af[4], bfr[2];
#pragma unroll
            for (int mi = 0; mi < 4; ++mi) {
                int row = wm + mi * 16 + l15;
                int ch  = (ks * 4 + quad) ^ (row & 7);
                af[mi] = *(const bf8_t*)(As + row * 64 + ch * 8);
            }
#pragma unroll
            for (int ni = 0; ni < 2; ++ni) {
                int row = wn + ni * 16 + l15;
                int ch  = (ks * 4 + quad) ^ (row & 7);
                bfr[ni] = *(const bf8_t*)(Bs + row * 64 + ch * 8);
            }
#pragma unroll
            for (int mi = 0; mi < 4; ++mi)
#pragma unroll
                for (int ni = 0; ni < 2; ++ni)
                    acc[mi][ni] = mfma16(af[mi], bfr[ni], acc[mi][ni]);
        }
        __syncthreads();
    }
}

// ---------- output projection: Ob @ Wo^T + bo -> out fp32 ----------
__global__ void __launch_bounds__(256) gemm_out(const __bf16* __restrict__ Ob,
                                                const __bf16* __restrict__ Wobf,
                                                const float* __restrict__ bo,
                                                float* __restrict__ out) {
    __shared__ __bf16 smem[128 * 64 + 64 * 64];
    __bf16* As = smem;
    __bf16* Bs = smem + 128 * 64;
    int m0 = ((int)blockIdx.x >> 4) * 128;
    int n0 = ((int)blockIdx.x & 15) * 64;
    f4_t acc[4][2];
    gemm_tile(Ob, Wobf, As, Bs, m0, n0, acc);
    const int lane = threadIdx.x & 63, wv = threadIdx.x >> 6;
    const int quad = lane >> 4, l15 = lane & 15;
    const int wm = (wv & 1) * 64, wn = (wv >> 1) * 32;
#pragma unroll
    for (int mi = 0; mi < 4; ++mi)
#pragma unroll
        for (int ni = 0; ni < 2; ++ni)
#pragma unroll
            for (int r = 0; r < 4; ++r) {
                int m = m0 + wm + mi * 16 + quad * 4 + r;
                int n = n0 + wn + ni * 16 + l15;
                out[(size_t)m * 1024 + n] = acc[mi][ni][r] + bo[n];
            }
}

// ---------- flash attention: cooperative, persistent, double-buffered --------
// scores = K.Q^T (ref quirk), causal s<=t, no max tracking (bounded scores,
// 0.125*log2e folded into K).  Block = 4 waves, 64-row t-tile, Q/V s-blocks
// staged once to LDS (shared).  Grid 512 = 2 blocks/CU; per-XCD queues hold
// 128 heavy-first items -> LPT balance (makespan ~33 s-iters every worker).
// Double-buffered staging: prefetch issued right AFTER the barrier so the
// vmcnt(0) drain at the NEXT barrier has the whole compute phase to cover it.
__global__ void __launch_bounds__(256, 2) attn(const __bf16* __restrict__ Kb,
                                               const __bf16* __restrict__ Qb,
                                               const __bf16* __restrict__ Vt,
                                               __bf16* __restrict__ Ob,
                                               int* __restrict__ ctrs) {
    __shared__ __bf16 Qs[2][64 * 64];
    __shared__ __bf16 Vs[2][64 * 64];
    __shared__ __bf16 Ps[4][16 * 72];
    __shared__ int item_lds;
    const int tid = threadIdx.x, lane = tid & 63, wv = tid >> 6;
    const int quad = lane >> 4, l15 = lane & 15;
    const int lrow8 = lane >> 3, lchunk = lane & 7;
    int xcc;
    asm volatile("s_getreg_b32 %0, hwreg(HW_REG_XCC_ID)" : "=s"(xcc));
    xcc &= 7;
    int* ctr = ctrs + xcc * 16;       // 64B-spaced per-XCD counters
    __bf16* Psw = &Ps[wv][0];
    f4_t zero = {0.f, 0.f, 0.f, 0.f};

    for (;;) {
        if (tid == 0) item_lds = atomicAdd(ctr, 1);
        __syncthreads();               // also protects Qs/Vs across items
        const int q = item_lds;
        if (q >= 128) break;
        const int tt = 31 - (q >> 2);         // heavy tiles first
        const int bh = xcc * 4 + (q & 3);     // this XCD's 4 heads
        const int b = bh >> 4, h = bh & 15;
        const int t0 = tt * 64;
        const int tw = t0 + wv * 16;
        const __bf16* Kp = Kb + (size_t)bh * 2048 * 64;
        const __bf16* Qp = Qb + (size_t)bh * 2048 * 64;
        const __bf16* Vp = Vt + (size_t)bh * 64 * 2048;

        // loop-invariant A-operand: K rows tw..tw+15 (pre-scaled), registers
        bf8_t kfrag[2];
#pragma unroll
        for (int ks = 0; ks < 2; ++ks)
            kfrag[ks] = *(const bf8_t*)(Kp + (size_t)(tw + l15) * 64 + ks * 32 + quad * 8);

        f4_t oacc[4];
#pragma unroll
        for (int ni = 0; ni < 4; ++ni) oacc[ni] = zero;
        float lsum[4] = {0.f, 0.f, 0.f, 0.f};

        auto stage = [&](int buf, int s0) {
#pragma unroll
            for (int j = 0; j < 2; ++j) {
                int row = wv * 8 + j * 32 + lrow8;
                int cg  = lchunk ^ (row & 7);
                async_ld16(Qp + (size_t)(s0 + row) * 64 + cg * 8,
                           &Qs[buf][(wv * 8 + j * 32) * 64]);
                async_ld16(Vp + (size_t)row * 2048 + s0 + cg * 8,
                           &Vs[buf][(wv * 8 + j * 32) * 64]);
            }
        };

        const int nsb = tt + 1;
        stage(0, 0);
        for (int sb = 0; sb < nsb; ++sb) {
            const int cur = sb & 1;
            const int s0 = sb * 64;
            const bool masked = (sb == nsb - 1);
            __syncthreads();           // drains staging of buf[cur]
            if (sb + 1 < nsb) stage(1 ^ cur, s0 + 64);   // flies during compute
            const __bf16* Qc = &Qs[cur][0];
            const __bf16* Vc = &Vs[cur][0];
            // ---- S = K.Q^T : 16 t-rows x 64 s-cols per wave
            f4_t sacc[4] = {zero, zero, zero, zero};
#pragma unroll
            for (int ks = 0; ks < 2; ++ks) {
                bf8_t qf[4];
#pragma unroll
                for (int st = 0; st < 4; ++st) {
                    int row = st * 16 + l15;
                    int ch  = (ks * 4 + quad) ^ (row & 7);
                    qf[st] = *(const bf8_t*)(Qc + row * 64 + ch * 8);
                }
#pragma unroll
                for (int st = 0; st < 4; ++st)
                    sacc[st] = mfma16(kfrag[ks], qf[st], sacc[st]);
            }
            // ---- exp2, mask, accumulate l, P -> LDS (C-layout to A-layout)
#pragma unroll
            for (int st = 0; st < 4; ++st)
#pragma unroll
                for (int r = 0; r < 4; ++r) {
                    float e = EXP2F(sacc[st][r]);
                    if (masked && (s0 + st * 16 + l15 > tw + quad * 4 + r)) e = 0.0f;
                    lsum[r] += e;
                    Psw[(quad * 4 + r) * 72 + st * 16 + l15] = (__bf16)e;
                }
            asm volatile("s_waitcnt lgkmcnt(0)" ::: "memory");
            bf8_t pf[2];
#pragma unroll
            for (int ks = 0; ks < 2; ++ks)
                pf[ks] = *(const bf8_t*)(Psw + l15 * 72 + ks * 32 + quad * 8);
            // ---- O += P @ V (V frags from LDS, shared across waves)
#pragma unroll
            for (int ks = 0; ks < 2; ++ks) {
                bf8_t vf[4];
#pragma unroll
                for (int ni = 0; ni < 4; ++ni) {
                    int row = ni * 16 + l15;
                    int ch  = (ks * 4 + quad) ^ (row & 7);
                    vf[ni] = *(const bf8_t*)(Vc + row * 64 + ch * 8);
                }
#pragma unroll
                for (int ni = 0; ni < 4; ++ni)
                    oacc[ni] = mfma16(pf[ks], vf[ni], oacc[ni]);
            }
        }

        // ---- epilogue: reduce l over the 16 s-lanes, normalize, write Ob
#pragma unroll
        for (int r = 0; r < 4; ++r) {
            float l = lsum[r];
            l += __shfl_xor(l, 1);
            l += __shfl_xor(l, 2);
            l += __shfl_xor(l, 4);
            l += __shfl_xor(l, 8);
            float inv = 1.0f / l;
            int t = tw + quad * 4 + r;
#pragma unroll
            for (int ni = 0; ni < 4; ++ni)
                Ob[((size_t)(b * 2048 + t) * 16 + h) * 64 + ni * 16 + l15] =
                    (__bf16)(oacc[ni][r] * inv);
        }
    }
}

// ---------- host ----------
extern "C" void kernel_launch(void* const* d_in, const int* in_sizes, int n_in,
                              void* d_out, int out_size, void* d_ws, size_t ws_size,
                              hipStream_t stream) {
    const float* X  = (const float*)d_in[0];
    const float* Wk = (const float*)d_in[1];
    const float* Wq = (const float*)d_in[2];
    const float* Wv = (const float*)d_in[3];
    const float* Wo = (const float*)d_in[4];
    const float* bo = (const float*)d_in[5];
    float* out = (float*)d_out;

    __bf16* ws   = (__bf16*)d_ws;
    __bf16* Xbf  = ws;                 // 4194304  (reused as queue counters in attn)
    __bf16* Wqt  = ws + 4194304;       // 1048576
    __bf16* Wkt  = ws + 5242880;       // 1048576
    __bf16* Wvt  = ws + 6291456;       // 1048576
    __bf16* Wobf = ws + 7340032;       // 1048576
    __bf16* Qb   = ws + 8388608;       // 4194304
    __bf16* Kb   = ws + 12582912;      // 4194304
    __bf16* Vt   = ws + 16777216;      // 4194304  (V^T: [B,H,D,T])
    __bf16* Ob   = ws + 20971520;      // 4194304  -> high-water 48 MiB (proven)
    int* ctrs = (int*)d_ws;            // 8 counters, 64B apart (Xbf dead by then)

    prep_convert<<<2560, 256, 0, stream>>>(X, Wo, Xbf, Wobf);
    wtrans<<<dim3(256, 3), 256, 0, stream>>>(Wq, Wk, Wv, Wqt, Wkt, Wvt);
    gemm_proj<<<dim3(256, 3), 256, 0, stream>>>(Xbf, Wqt, Wkt, Wvt, Qb, Kb, Vt);
    hipMemsetAsync(ctrs, 0, 512, stream);
    attn<<<512, 256, 0, stream>>>(Kb, Qb, Vt, Ob, ctrs);
    gemm_out<<<512, 256, 0, stream>>>(Ob, Wobf, bo, out);
}

// Round 7
// 171.853 us; speedup vs baseline: 1.1014x; 1.1014x over previous
//
#include <hip/hip_runtime.h>
#include <cstdint>
#include <cstddef>

// ---------- types ----------
typedef __bf16 bf8_t __attribute__((ext_vector_type(8)));
typedef float  f4_t  __attribute__((ext_vector_type(4)));

static __device__ __forceinline__ f4_t mfma16(bf8_t a, bf8_t b, f4_t c) {
    return __builtin_amdgcn_mfma_f32_16x16x32_bf16(a, b, c, 0, 0, 0);
}

#if defined(__has_builtin) && __has_builtin(__builtin_amdgcn_exp2f)
#define EXP2F(x) __builtin_amdgcn_exp2f(x)
#else
#define EXP2F(x) exp2f(x)
#endif

// global -> LDS direct DMA, 16B per lane (wave-uniform base, lane i at base+i*16)
static __device__ __forceinline__ void async_ld16(const __bf16* g, __bf16* l) {
    __builtin_amdgcn_global_load_lds(
        (const __attribute__((address_space(1))) void*)(uintptr_t)g,
        (__attribute__((address_space(3))) void*)(uintptr_t)l, 16, 0, 0);
}

// B=2, T=2048, E=1024, H=16, D=64.  M = B*T = 4096.

// ---------- prep (fused): fp32->bf16 X & Wo, plus W[H,E,D] -> Wt[H*D,E] ------
// blocks 0..2559: convert X/Wo.  blocks 2560..3327: transpose Wq/Wk/Wv.
__global__ void __launch_bounds__(256) prep_all(const float* __restrict__ X,
                                                const float* __restrict__ Wo,
                                                const float* __restrict__ Wq,
                                                const float* __restrict__ Wk,
                                                const float* __restrict__ Wv,
                                                __bf16* __restrict__ Xbf,
                                                __bf16* __restrict__ Wobf,
                                                __bf16* __restrict__ Wqt,
                                                __bf16* __restrict__ Wkt,
                                                __bf16* __restrict__ Wvt) {
    __shared__ float tile[64][65];
    int bx = (int)blockIdx.x;
    if (bx < 2560) {
        const float* src; __bf16* dst; size_t base;
        if (bx < 2048) { src = X;  dst = Xbf;  base = (size_t)bx * 2048; }
        else           { src = Wo; dst = Wobf; base = (size_t)(bx - 2048) * 2048; }
        size_t i = base + (size_t)threadIdx.x * 8;
        float4 a = *(const float4*)(src + i);
        float4 b = *(const float4*)(src + i + 4);
        bf8_t o;
        o[0] = (__bf16)a.x; o[1] = (__bf16)a.y; o[2] = (__bf16)a.z; o[3] = (__bf16)a.w;
        o[4] = (__bf16)b.x; o[5] = (__bf16)b.y; o[6] = (__bf16)b.z; o[7] = (__bf16)b.w;
        *(bf8_t*)(dst + i) = o;
        return;
    }
    int wt = bx - 2560;                 // 0..767
    int which = wt >> 8, inner = wt & 255;
    const float* W; __bf16* Wt;
    if (which == 0)      { W = Wq; Wt = Wqt; }
    else if (which == 1) { W = Wk; Wt = Wkt; }
    else                 { W = Wv; Wt = Wvt; }
    int h = inner >> 4, eb = inner & 15;
    int tx = threadIdx.x;
    int e = tx >> 2, dg = (tx & 3) * 16;
    const float* src = W + ((size_t)h * 1024 + eb * 64 + e) * 64 + dg;
#pragma unroll
    for (int i = 0; i < 4; ++i) {
        float4 v = *(const float4*)(src + i * 4);
        tile[dg + i * 4 + 0][e] = v.x;
        tile[dg + i * 4 + 1][e] = v.y;
        tile[dg + i * 4 + 2][e] = v.z;
        tile[dg + i * 4 + 3][e] = v.w;
    }
    __syncthreads();
    int d = tx >> 2, eg = (tx & 3) * 16;
    __bf16* dst = Wt + (size_t)(h * 64 + d) * 1024 + eb * 64 + eg;
    bf8_t o0, o1;
#pragma unroll
    for (int i = 0; i < 8; ++i) o0[i] = (__bf16)tile[d][eg + i];
#pragma unroll
    for (int i = 0; i < 8; ++i) o1[i] = (__bf16)tile[d][eg + 8 + i];
    *(bf8_t*)dst       = o0;
    *(bf8_t*)(dst + 8) = o1;
}

// ---------- m97-style mainloop: C[128x128] tile of A[M,1024] x Bt[N,1024]^T ----
// 4 waves in 2x2, each wave 64x64 via 4x4 16x16 frags. BK=64.
static __device__ __forceinline__ void gemm_tile128(const __bf16* __restrict__ A,
                                                    const __bf16* __restrict__ Bt,
                                                    __bf16* As, __bf16* Bs,
                                                    int m0, int n0, f4_t acc[4][4]) {
    const int tid  = threadIdx.x;
    const int lane = tid & 63;
    const int wv   = tid >> 6;
    const int lrow = lane >> 3;
    const int lsc  = lane & 7;
    const int quad = lane >> 4;
    const int l15  = lane & 15;
    const int wm = (wv & 1) * 64;
    const int wn = (wv >> 1) * 64;
    f4_t zero = {0.f, 0.f, 0.f, 0.f};
#pragma unroll
    for (int mi = 0; mi < 4; ++mi)
#pragma unroll
        for (int ni = 0; ni < 4; ++ni) acc[mi][ni] = zero;

    for (int kb = 0; kb < 16; ++kb) {
#pragma unroll
        for (int j = 0; j < 4; ++j) {
            int row = wv * 32 + j * 8 + lrow;
            int lc  = lsc ^ (row & 7);
            async_ld16(A + (size_t)(m0 + row) * 1024 + kb * 64 + lc * 8,
                       As + (wv * 32 + j * 8) * 64);
            async_ld16(Bt + (size_t)(n0 + row) * 1024 + kb * 64 + lc * 8,
                       Bs + (wv * 32 + j * 8) * 64);
        }
        __syncthreads();
#pragma unroll
        for (int ks = 0; ks < 2; ++ks) {
            bf8_t af[4], bfr[4];
#pragma unroll
            for (int mi = 0; mi < 4; ++mi) {
                int row = wm + mi * 16 + l15;
                int ch  = (ks * 4 + quad) ^ (row & 7);
                af[mi] = *(const bf8_t*)(As + row * 64 + ch * 8);
            }
#pragma unroll
            for (int ni = 0; ni < 4; ++ni) {
                int row = wn + ni * 16 + l15;
                int ch  = (ks * 4 + quad) ^ (row & 7);
                bfr[ni] = *(const bf8_t*)(Bs + row * 64 + ch * 8);
            }
#pragma unroll
            for (int mi = 0; mi < 4; ++mi)
#pragma unroll
                for (int ni = 0; ni < 4; ++ni)
                    acc[mi][ni] = mfma16(af[mi], bfr[ni], acc[mi][ni]);
        }
        __syncthreads();
    }
}

// ---------- projections: X @ W{q,k,v}. Q,K -> [B,H,T,D]; V -> V^T [B,H,D,T].
// K is pre-scaled by 0.125*log2(e) so attention can use exp2 directly.
// ALL epilogues route through LDS for 16B coalesced stores.
__global__ void __launch_bounds__(256, 3) gemm_proj(const __bf16* __restrict__ Xbf,
                                                    const __bf16* __restrict__ Wqt,
                                                    const __bf16* __restrict__ Wkt,
                                                    const __bf16* __restrict__ Wvt,
                                                    __bf16* __restrict__ Qb,
                                                    __bf16* __restrict__ Kb,
                                                    __bf16* __restrict__ Vt) {
    __shared__ __bf16 smem[17408];     // union: As(8192)+Bs(8192) | 128x136 epilogue
    __bf16* As = smem;
    __bf16* Bs = smem + 8192;
    int which = blockIdx.y;
    const __bf16* Bt = which == 0 ? Wqt : (which == 1 ? Wkt : Wvt);
    int m0 = ((int)blockIdx.x >> 3) * 128;
    int n0 = ((int)blockIdx.x & 7) * 128;
    f4_t acc[4][4];
    gemm_tile128(Xbf, Bt, As, Bs, m0, n0, acc);
    const int lane = threadIdx.x & 63, wv = threadIdx.x >> 6;
    const int quad = lane >> 4, l15 = lane & 15;
    const int wm = (wv & 1) * 64, wn = (wv >> 1) * 64;
    const int STR = 136;
    if (which < 2) {
        __bf16* C = which ? Kb : Qb;
        const float scl = which ? 0.18033688f : 1.0f;   // 0.125 * log2(e) folded into K
        // acc -> LDS [m_loc][n_loc] (after final barrier of mainloop, smem is free)
#pragma unroll
        for (int mi = 0; mi < 4; ++mi)
#pragma unroll
            for (int ni = 0; ni < 4; ++ni)
#pragma unroll
                for (int r = 0; r < 4; ++r) {
                    int ml = wm + mi * 16 + quad * 4 + r;
                    int nl = wn + ni * 16 + l15;
                    smem[ml * STR + nl] = (__bf16)(acc[mi][ni][r] * scl);
                }
        __syncthreads();
        // each thread stores one (row, head-half): 8 x 16B
        int row = (int)threadIdx.x >> 1;          // 0..127
        int seg = (int)threadIdx.x & 1;           // which 64-col half (one head)
        int m = m0 + row;
        int b = m >> 11, t = m & 2047;
        int h = (n0 >> 6) + seg;
        __bf16* dst = C + ((size_t)(b * 16 + h) * 2048 + t) * 64;
        const __bf16* srcl = smem + row * STR + seg * 64;
#pragma unroll
        for (int k = 0; k < 8; ++k)
            *(bf8_t*)(dst + k * 8) = *(const bf8_t*)(srcl + k * 8);
    } else {
        // V^T epilogue: acc -> LDS [n_loc][m_loc] -> coalesced rows of Vt
#pragma unroll
        for (int mi = 0; mi < 4; ++mi)
#pragma unroll
            for (int ni = 0; ni < 4; ++ni)
#pragma unroll
                for (int r = 0; r < 4; ++r) {
                    int ml = wm + mi * 16 + quad * 4 + r;   // 0..127 (t)
                    int nl = wn + ni * 16 + l15;            // 0..127 (h,d)
                    smem[nl * STR + ml] = (__bf16)acc[mi][ni][r];
                }
        __syncthreads();
        int b = m0 >> 11, tg0 = m0 & 2047;
        int nl = (int)threadIdx.x >> 1;
        int tc = ((int)threadIdx.x & 1) * 64;
        int n = n0 + nl, h = n >> 6, d = n & 63;
        __bf16* dst = Vt + ((size_t)(b * 16 + h) * 64 + d) * 2048 + tg0 + tc;
        const __bf16* srcl = smem + nl * STR + tc;
#pragma unroll
        for (int k = 0; k < 8; ++k)
            *(bf8_t*)(dst + k * 8) = *(const bf8_t*)(srcl + k * 8);
    }
}

// ---------- GEMM mainloop (128x64 tile) for gemm_out (grid 512 = 2/CU) -------
static __device__ __forceinline__ void gemm_tile(const __bf16* __restrict__ A,
                                                 const __bf16* __restrict__ Bt,
                                                 __bf16* As, __bf16* Bs,
                                                 int m0, int n0, f4_t acc[4][2]) {
    const int tid  = threadIdx.x;
    const int lane = tid & 63;
    const int wv   = tid >> 6;
    const int lrow = lane >> 3;
    const int lsc  = lane & 7;
    const int quad = lane >> 4;
    const int l15  = lane & 15;
    const int wm = (wv & 1) * 64;
    const int wn = (wv >> 1) * 32;
    f4_t zero = {0.f, 0.f, 0.f, 0.f};
#pragma unroll
    for (int mi = 0; mi < 4; ++mi)
#pragma unroll
        for (int ni = 0; ni < 2; ++ni) acc[mi][ni] = zero;

    for (int kb = 0; kb < 16; ++kb) {
#pragma unroll
        for (int j = 0; j < 4; ++j) {
            int row = wv * 32 + j * 8 + lrow;
            int lc  = lsc ^ (row & 7);
            async_ld16(A + (size_t)(m0 + row) * 1024 + kb * 64 + lc * 8,
                       As + (wv * 32 + j * 8) * 64);
        }
#pragma unroll
        for (int j = 0; j < 2; ++j) {
            int row = wv * 16 + j * 8 + lrow;
            int lc  = lsc ^ (row & 7);
            async_ld16(Bt + (size_t)(n0 + row) * 1024 + kb * 64 + lc * 8,
                       Bs + (wv * 16 + j * 8) * 64);
        }
        __syncthreads();
#pragma unroll
        for (int ks = 0; ks < 2; ++ks) {
            bf8_t af[4], bfr[2];
#pragma unroll
            for (int mi = 0; mi < 4; ++mi) {
                int row = wm + mi * 16 + l15;
                int ch  = (ks * 4 + quad) ^ (row & 7);
                af[mi] = *(const bf8_t*)(As + row * 64 + ch * 8);
            }
#pragma unroll
            for (int ni = 0; ni < 2; ++ni) {
                int row = wn + ni * 16 + l15;
                int ch  = (ks * 4 + quad) ^ (row & 7);
                bfr[ni] = *(const bf8_t*)(Bs + row * 64 + ch * 8);
            }
#pragma unroll
            for (int mi = 0; mi < 4; ++mi)
#pragma unroll
                for (int ni = 0; ni < 2; ++ni)
                    acc[mi][ni] = mfma16(af[mi], bfr[ni], acc[mi][ni]);
        }
        __syncthreads();
    }
}

// ---------- output projection: Ob @ Wo^T + bo -> out fp32 ----------
__global__ void __launch_bounds__(256) gemm_out(const __bf16* __restrict__ Ob,
                                                const __bf16* __restrict__ Wobf,
                                                const float* __restrict__ bo,
                                                float* __restrict__ out) {
    __shared__ __bf16 smem[128 * 64 + 64 * 64];
    __bf16* As = smem;
    __bf16* Bs = smem + 128 * 64;
    int m0 = ((int)blockIdx.x >> 4) * 128;
    int n0 = ((int)blockIdx.x & 15) * 64;
    f4_t acc[4][2];
    gemm_tile(Ob, Wobf, As, Bs, m0, n0, acc);
    const int lane = threadIdx.x & 63, wv = threadIdx.x >> 6;
    const int quad = lane >> 4, l15 = lane & 15;
    const int wm = (wv & 1) * 64, wn = (wv >> 1) * 32;
#pragma unroll
    for (int mi = 0; mi < 4; ++mi)
#pragma unroll
        for (int ni = 0; ni < 2; ++ni)
#pragma unroll
            for (int r = 0; r < 4; ++r) {
                int m = m0 + wm + mi * 16 + quad * 4 + r;
                int n = n0 + wn + ni * 16 + l15;
                out[(size_t)m * 1024 + n] = acc[mi][ni][r] + bo[n];
            }
}

// ---------- flash attention: cooperative, persistent, double-buffered --------
// scores = K.Q^T (ref quirk), causal s<=t, no max tracking (bounded scores,
// 0.125*log2e folded into K).  Block = 4 waves, 64-row t-tile, Q/V s-blocks
// double-buffer staged to LDS (shared by all 4 waves).  Grid 768 = 3 blocks/CU
// (12 waves/CU for latency hiding); per-XCD queues hold 128 heavy-first items
// (makespan bounded by heaviest item = 32 s-iters).
__global__ void __launch_bounds__(256, 3) attn(const __bf16* __restrict__ Kb,
                                               const __bf16* __restrict__ Qb,
                                               const __bf16* __restrict__ Vt,
                                               __bf16* __restrict__ Ob,
                                               int* __restrict__ ctrs) {
    __shared__ __bf16 Qs[2][64 * 64];
    __shared__ __bf16 Vs[2][64 * 64];
    __shared__ __bf16 Ps[4][16 * 72];
    __shared__ int item_lds;
    const int tid = threadIdx.x, lane = tid & 63, wv = tid >> 6;
    const int quad = lane >> 4, l15 = lane & 15;
    const int lrow8 = lane >> 3, lchunk = lane & 7;
    int xcc;
    asm volatile("s_getreg_b32 %0, hwreg(HW_REG_XCC_ID)" : "=s"(xcc));
    xcc &= 7;
    int* ctr = ctrs + xcc * 16;       // 64B-spaced per-XCD counters
    __bf16* Psw = &Ps[wv][0];
    f4_t zero = {0.f, 0.f, 0.f, 0.f};

    for (;;) {
        if (tid == 0) item_lds = atomicAdd(ctr, 1);
        __syncthreads();               // also protects Qs/Vs across items
        const int q = item_lds;
        if (q >= 128) break;
        const int tt = 31 - (q >> 2);         // heavy tiles first
        const int bh = xcc * 4 + (q & 3);     // this XCD's 4 heads
        const int b = bh >> 4, h = bh & 15;
        const int t0 = tt * 64;
        const int tw = t0 + wv * 16;
        const __bf16* Kp = Kb + (size_t)bh * 2048 * 64;
        const __bf16* Qp = Qb + (size_t)bh * 2048 * 64;
        const __bf16* Vp = Vt + (size_t)bh * 64 * 2048;

        // loop-invariant A-operand: K rows tw..tw+15 (pre-scaled), registers
        bf8_t kfrag[2];
#pragma unroll
        for (int ks = 0; ks < 2; ++ks)
            kfrag[ks] = *(const bf8_t*)(Kp + (size_t)(tw + l15) * 64 + ks * 32 + quad * 8);

        f4_t oacc[4];
#pragma unroll
        for (int ni = 0; ni < 4; ++ni) oacc[ni] = zero;
        float lsum[4] = {0.f, 0.f, 0.f, 0.f};

        auto stage = [&](int buf, int s0) {
#pragma unroll
            for (int j = 0; j < 2; ++j) {
                int row = wv * 8 + j * 32 + lrow8;
                int cg  = lchunk ^ (row & 7);
                async_ld16(Qp + (size_t)(s0 + row) * 64 + cg * 8,
                           &Qs[buf][(wv * 8 + j * 32) * 64]);
                async_ld16(Vp + (size_t)row * 2048 + s0 + cg * 8,
                           &Vs[buf][(wv * 8 + j * 32) * 64]);
            }
        };

        const int nsb = tt + 1;
        stage(0, 0);
        for (int sb = 0; sb < nsb; ++sb) {
            const int cur = sb & 1;
            const int s0 = sb * 64;
            const bool masked = (sb == nsb - 1);
            __syncthreads();           // drains staging of buf[cur]
            if (sb + 1 < nsb) stage(1 ^ cur, s0 + 64);   // flies during compute
            const __bf16* Qc = &Qs[cur][0];
            const __bf16* Vc = &Vs[cur][0];
            // ---- S = K.Q^T : 16 t-rows x 64 s-cols per wave
            f4_t sacc[4] = {zero, zero, zero, zero};
#pragma unroll
            for (int ks = 0; ks < 2; ++ks) {
                bf8_t qf[4];
#pragma unroll
                for (int st = 0; st < 4; ++st) {
                    int row = st * 16 + l15;
                    int ch  = (ks * 4 + quad) ^ (row & 7);
                    qf[st] = *(const bf8_t*)(Qc + row * 64 + ch * 8);
                }
#pragma unroll
                for (int st = 0; st < 4; ++st)
                    sacc[st] = mfma16(kfrag[ks], qf[st], sacc[st]);
            }
            // ---- exp2, mask, accumulate l, P -> LDS (C-layout to A-layout)
#pragma unroll
            for (int st = 0; st < 4; ++st)
#pragma unroll
                for (int r = 0; r < 4; ++r) {
                    float e = EXP2F(sacc[st][r]);
                    if (masked && (s0 + st * 16 + l15 > tw + quad * 4 + r)) e = 0.0f;
                    lsum[r] += e;
                    Psw[(quad * 4 + r) * 72 + st * 16 + l15] = (__bf16)e;
                }
            asm volatile("s_waitcnt lgkmcnt(0)" ::: "memory");
            bf8_t pf[2];
#pragma unroll
            for (int ks = 0; ks < 2; ++ks)
                pf[ks] = *(const bf8_t*)(Psw + l15 * 72 + ks * 32 + quad * 8);
            // ---- O += P @ V (V frags from LDS, shared across waves)
#pragma unroll
            for (int ks = 0; ks < 2; ++ks) {
                bf8_t vf[4];
#pragma unroll
                for (int ni = 0; ni < 4; ++ni) {
                    int row = ni * 16 + l15;
                    int ch  = (ks * 4 + quad) ^ (row & 7);
                    vf[ni] = *(const bf8_t*)(Vc + row * 64 + ch * 8);
                }
#pragma unroll
                for (int ni = 0; ni < 4; ++ni)
                    oacc[ni] = mfma16(pf[ks], vf[ni], oacc[ni]);
            }
        }

        // ---- epilogue: reduce l over the 16 s-lanes, normalize, write Ob
#pragma unroll
        for (int r = 0; r < 4; ++r) {
            float l = lsum[r];
            l += __shfl_xor(l, 1);
            l += __shfl_xor(l, 2);
            l += __shfl_xor(l, 4);
            l += __shfl_xor(l, 8);
            float inv = 1.0f / l;
            int t = tw + quad * 4 + r;
#pragma unroll
            for (int ni = 0; ni < 4; ++ni)
                Ob[((size_t)(b * 2048 + t) * 16 + h) * 64 + ni * 16 + l15] =
                    (__bf16)(oacc[ni][r] * inv);
        }
    }
}

// ---------- host ----------
extern "C" void kernel_launch(void* const* d_in, const int* in_sizes, int n_in,
                              void* d_out, int out_size, void* d_ws, size_t ws_size,
                              hipStream_t stream) {
    const float* X  = (const float*)d_in[0];
    const float* Wk = (const float*)d_in[1];
    const float* Wq = (const float*)d_in[2];
    const float* Wv = (const float*)d_in[3];
    const float* Wo = (const float*)d_in[4];
    const float* bo = (const float*)d_in[5];
    float* out = (float*)d_out;

    __bf16* ws   = (__bf16*)d_ws;
    __bf16* Xbf  = ws;                 // 4194304  (reused as queue counters in attn)
    __bf16* Wqt  = ws + 4194304;       // 1048576
    __bf16* Wkt  = ws + 5242880;       // 1048576
    __bf16* Wvt  = ws + 6291456;       // 1048576
    __bf16* Wobf = ws + 7340032;       // 1048576
    __bf16* Qb   = ws + 8388608;       // 4194304
    __bf16* Kb   = ws + 12582912;      // 4194304
    __bf16* Vt   = ws + 16777216;      // 4194304  (V^T: [B,H,D,T])
    __bf16* Ob   = ws + 20971520;      // 4194304  -> high-water 48 MiB (proven)
    int* ctrs = (int*)d_ws;            // 8 counters, 64B apart (Xbf dead by then)

    prep_all<<<3328, 256, 0, stream>>>(X, Wo, Wq, Wk, Wv, Xbf, Wobf, Wqt, Wkt, Wvt);
    gemm_proj<<<dim3(256, 3), 256, 0, stream>>>(Xbf, Wqt, Wkt, Wvt, Qb, Kb, Vt);
    hipMemsetAsync(ctrs, 0, 512, stream);
    attn<<<768, 256, 0, stream>>>(Kb, Qb, Vt, Ob, ctrs);
    gemm_out<<<512, 256, 0, stream>>>(Ob, Wobf, bo, out);
}